// Round 1
// baseline (970.287 us; speedup 1.0000x reference)
//
#include <hip/hip_runtime.h>
#include <hip/hip_bf16.h>

// GCN 2-layer: out = relu(Dinv(A+I)Dinv (relu(Dinv(A+I)Dinv (x@W1)+b1) @ W2)+b2)
// Factoring: hs = (x@W)*dinv[row];  agg[d] += hs[s] over edges;
//            next = relu(dinv[d]*(agg[d] + hs[d]) + b)

#define NDIM 64  // feature dim, fixed by the problem

// ---- degree count: one thread per edge, float atomic increment ----
__global__ __launch_bounds__(256) void count_deg_kernel(
    const int* __restrict__ dst, float* __restrict__ deg, int nedges) {
  int e = blockIdx.x * 256 + threadIdx.x;
  if (e < nedges) atomicAdd(&deg[dst[e]], 1.0f);
}

// ---- dinv = rsqrt(deg + 1)  (in-place on deg buffer) ----
__global__ __launch_bounds__(256) void dinv_kernel(float* __restrict__ deg, int n) {
  int i = blockIdx.x * 256 + threadIdx.x;
  if (i < n) deg[i] = rsqrtf(deg[i] + 1.0f);
}

// ---- hs = (X @ W) * dinv[row] ; X:[n,64] W:[64,64] ----
__global__ __launch_bounds__(256) void gemm_rowscale_kernel(
    const float* __restrict__ X, const float* __restrict__ W,
    const float* __restrict__ dinv, float* __restrict__ out, int nrows) {
  __shared__ float sW[NDIM * NDIM];
  __shared__ float sX[NDIM * NDIM];
  int tid = threadIdx.x;
  int row0 = blockIdx.x * NDIM;
  for (int i = tid; i < NDIM * NDIM; i += 256) sW[i] = W[i];
  for (int i = tid; i < NDIM * NDIM; i += 256) {
    int r = row0 + (i >> 6);
    sX[i] = (r < nrows) ? X[(size_t)r * NDIM + (i & 63)] : 0.0f;
  }
  __syncthreads();
  int c = tid & 63;       // output column = lane
  int r0 = tid >> 6;      // 0..3
  for (int rr = r0; rr < NDIM; rr += 4) {
    float acc = 0.0f;
#pragma unroll
    for (int k = 0; k < NDIM; ++k) acc += sX[rr * NDIM + k] * sW[k * NDIM + c];
    int r = row0 + rr;
    if (r < nrows) out[(size_t)r * NDIM + c] = acc * dinv[r];
  }
}

// ---- agg[dst] += hs[src] : one wave per edge, lane = column ----
__global__ __launch_bounds__(256) void aggregate_kernel(
    const int* __restrict__ src, const int* __restrict__ dst,
    const float* __restrict__ hs, float* __restrict__ agg, int nedges) {
  int t = blockIdx.x * 256 + threadIdx.x;
  int e = t >> 6;
  int c = t & 63;
  if (e >= nedges) return;
  int s = src[e];
  int d = dst[e];
  float v = hs[(size_t)s * NDIM + c];
  atomicAdd(&agg[(size_t)d * NDIM + c], v);
}

// ---- out = relu(dinv[row] * (agg + hs) + b[col]) ----
__global__ __launch_bounds__(256) void epilogue_kernel(
    const float* __restrict__ agg, const float* __restrict__ hs,
    const float* __restrict__ dinv, const float* __restrict__ b,
    float* __restrict__ out, int n) {  // n = nrows*64
  int i = blockIdx.x * 256 + threadIdx.x;
  if (i >= n) return;
  int row = i >> 6;
  int c = i & 63;
  float v = dinv[row] * (agg[i] + hs[i]) + b[c];
  out[i] = v > 0.0f ? v : 0.0f;
}

extern "C" void kernel_launch(void* const* d_in, const int* in_sizes, int n_in,
                              void* d_out, int out_size, void* d_ws, size_t ws_size,
                              hipStream_t stream) {
  const float* x  = (const float*)d_in[0];
  const int* eidx = (const int*)d_in[1];   // [2, E] int32
  const float* W1 = (const float*)d_in[2];
  const float* b1 = (const float*)d_in[3];
  const float* W2 = (const float*)d_in[4];
  const float* b2 = (const float*)d_in[5];
  float* out = (float*)d_out;

  const int N = in_sizes[0] / NDIM;      // 100000
  const int E = in_sizes[1] / 2;         // 1600000
  const int* src = eidx;
  const int* dst = eidx + E;

  // workspace layout (floats)
  float* ws = (float*)d_ws;
  float* dinv = ws;                        // N
  float* hs   = ws + N;                    // N*64  (gemm output, dinv-scaled)
  float* agg  = hs + (size_t)N * NDIM;     // N*64
  float* h2   = agg + (size_t)N * NDIM;    // N*64  (layer-1 activation)

  const int NV = N * NDIM;

  // ---- degrees ----
  hipMemsetAsync(dinv, 0, (size_t)N * sizeof(float), stream);
  count_deg_kernel<<<(E + 255) / 256, 256, 0, stream>>>(dst, dinv, E);
  dinv_kernel<<<(N + 255) / 256, 256, 0, stream>>>(dinv, N);

  // ---- layer 1 ----
  gemm_rowscale_kernel<<<(N + NDIM - 1) / NDIM, 256, 0, stream>>>(x, W1, dinv, hs, N);
  hipMemsetAsync(agg, 0, (size_t)NV * sizeof(float), stream);
  aggregate_kernel<<<(int)(((size_t)E * 64 + 255) / 256), 256, 0, stream>>>(src, dst, hs, agg, E);
  epilogue_kernel<<<(NV + 255) / 256, 256, 0, stream>>>(agg, hs, dinv, b1, h2, NV);

  // ---- layer 2 ----
  gemm_rowscale_kernel<<<(N + NDIM - 1) / NDIM, 256, 0, stream>>>(h2, W2, dinv, hs, N);
  hipMemsetAsync(agg, 0, (size_t)NV * sizeof(float), stream);
  aggregate_kernel<<<(int)(((size_t)E * 64 + 255) / 256), 256, 0, stream>>>(src, dst, hs, agg, E);
  epilogue_kernel<<<(NV + 255) / 256, 256, 0, stream>>>(agg, hs, dinv, b2, out, NV);
}